// Round 5
// baseline (796.815 us; speedup 1.0000x reference)
//
#include <hip/hip_runtime.h>

typedef unsigned short u16;
typedef __attribute__((ext_vector_type(8))) short short8;
typedef __attribute__((ext_vector_type(4))) float f32x4;
typedef __attribute__((ext_vector_type(16))) float f32x16;
typedef __attribute__((ext_vector_type(2))) unsigned int u32x2;

#define NPTS 1048576
#define HP 264  // sH row stride in elements (528 B, 16B-aligned)

// round-to-nearest (half away from zero): 2 VALU ops, <=0.5 ulp
__device__ __forceinline__ u16 f2b(float f) {
    return (u16)((__float_as_uint(f) + 0x8000u) >> 16);
}
#define INV2PI 0.15915494309189535f
// sin with argument in revolutions; v_sin_f32 wants fract-reduced input
__device__ __forceinline__ float sinrev(float t) {
    t = t - floorf(t);
    return __builtin_amdgcn_sinf(t);
}

// ---------------- weight convert(fp32->bf16) + transpose/pad prepass ----------------
// ws layout (bf16 elements), WT[n][k] row-major in k:
//  WT1  @      0 : 256 x  64   (from W1  63x256; k==63 holds b1[n] — bias fold, act col63=1.0)
//  WT2  @  16384 : 256 x 256   (from W2 256x256)
//  WT3  @  81920 : 256 x 256   (from W3 256x256)
//  WT4  @ 147456 :  16 x 256   (from W4 256x16)
//  WTc1 @ 151552 : 128 x  64   (from Wc1 42x128; k==42 holds bc1[n] — bias fold; k>42 -> 0)
//  WTc2 @ 159744 :  16 x 128   (from Wc2 128x3, n>=3 -> 0)
__global__ void prep_weights(const float* __restrict__ W1, const float* __restrict__ b1,
                             const float* __restrict__ W2,
                             const float* __restrict__ W3, const float* __restrict__ W4,
                             const float* __restrict__ Wc1, const float* __restrict__ bc1,
                             const float* __restrict__ Wc2,
                             u16* __restrict__ ws) {
    int i = blockIdx.x * 256 + threadIdx.x;
    if (i < 16384) { int n = i >> 6, k = i & 63;  ws[i]          = (k < 63) ? f2b(W1[k * 256 + n]) : f2b(b1[n]); return; }
    i -= 16384;
    if (i < 65536) { int n = i >> 8, k = i & 255; ws[16384 + i]  = f2b(W2[k * 256 + n]); return; }
    i -= 65536;
    if (i < 65536) { int n = i >> 8, k = i & 255; ws[81920 + i]  = f2b(W3[k * 256 + n]); return; }
    i -= 65536;
    if (i < 4096)  { int n = i >> 8, k = i & 255; ws[147456 + i] = f2b(W4[k * 16 + n]); return; }
    i -= 4096;
    if (i < 8192)  { int n = i >> 6, k = i & 63;
                     ws[151552 + i] = (k < 42) ? f2b(Wc1[k * 128 + n]) : ((k == 42) ? f2b(bc1[n]) : (u16)0); return; }
    i -= 8192;
    if (i < 2048)  { int n = i >> 7, k = i & 127; ws[159744 + i] = (n < 3) ? f2b(Wc2[k * 3 + n]) : (u16)0; return; }
}

// ---------------- fused dense layer, 32x32x16 MFMA, A=weights B=activations ----------------
// A frag (weights):    m(neuron)=lane&31, k=(lane>>5)*8+j — 16B contig from WT[m][k] (global)
// B frag (activation): n(batchrow)=lane&31, k=(lane>>5)*8+j — 16B contig from sH row (LDS)
// D: col(batchrow)=lane&31, row(neuron m)=(reg&3)+8*(reg>>2)+4*(lane>>5) within 32-tile.
// => lane holds ONE batch row and reg-quads of 4 CONSECUTIVE neurons = 4 consecutive
// k-slots of next layer's sH row -> packed ds_write_b64 epilogue (4x fewer LDS writes).
// Wave: batch rows [row0,row0+64) as 2 bt-tiles, neurons [nbase, nbase+NT*32).
// All LDS reads precede the internal barrier; writes follow it -> in-place safe.
template <int K, int NT, bool RELU, bool BIAS>
__device__ __forceinline__ void dense32(const u16* __restrict__ WT, const float* __restrict__ bias,
                                        u16 (*sH)[HP], int row0, int nbase, int lane) {
    constexpr int NKT = K / 16;
    const int ln = lane & 31, kh = lane >> 5;
    f32x16 acc[2][NT];
#pragma unroll
    for (int bt = 0; bt < 2; ++bt)
#pragma unroll
        for (int nt = 0; nt < NT; ++nt)
#pragma unroll
            for (int r = 0; r < 16; ++r) acc[bt][nt][r] = 0.f;
#pragma unroll
    for (int kt = 0; kt < NKT; ++kt) {
        short8 bAct[2];
#pragma unroll
        for (int bt = 0; bt < 2; ++bt)
            bAct[bt] = *(const short8*)&sH[row0 + bt * 32 + ln][kt * 16 + kh * 8];
#pragma unroll
        for (int nt = 0; nt < NT; ++nt) {
            const short8 aW = *(const short8*)(WT + (size_t)(nbase + nt * 32 + ln) * K + kt * 16 + kh * 8);
#pragma unroll
            for (int bt = 0; bt < 2; ++bt)
                acc[bt][nt] = __builtin_amdgcn_mfma_f32_32x32x16_bf16(aW, bAct[bt], acc[bt][nt], 0, 0, 0);
        }
    }
    __syncthreads();
#pragma unroll
    for (int bt = 0; bt < 2; ++bt) {
        u16* rowp = &sH[row0 + bt * 32 + ln][0];
#pragma unroll
        for (int nt = 0; nt < NT; ++nt)
#pragma unroll
            for (int g = 0; g < 4; ++g) {
                const int mq = nbase + nt * 32 + 8 * g + 4 * kh;   // 4 consecutive neurons
                float v[4];
#pragma unroll
                for (int j = 0; j < 4; ++j) v[j] = acc[bt][nt][4 * g + j];
                if (BIAS) {
                    const f32x4 bi = *(const f32x4*)(bias + mq);
#pragma unroll
                    for (int j = 0; j < 4; ++j) v[j] += bi[j];
                }
                if (RELU)
#pragma unroll
                    for (int j = 0; j < 4; ++j) v[j] = fmaxf(v[j], 0.f);
                unsigned int u[4];
#pragma unroll
                for (int j = 0; j < 4; ++j) u[j] = __float_as_uint(v[j]) + 0x8000u;
                u32x2 d;
                d.x = __builtin_amdgcn_perm(u[1], u[0], 0x07060302);  // {hi16(u1), hi16(u0)}
                d.y = __builtin_amdgcn_perm(u[3], u[2], 0x07060302);
                *(u32x2*)(rowp + mq) = d;   // ds_write_b64
            }
    }
}

__global__ __launch_bounds__(512, 4) void ngp_fused(
    const float* __restrict__ pos, const float* __restrict__ dir, const u16* __restrict__ ws,
    const float* __restrict__ b2, const float* __restrict__ b3,
    const float* __restrict__ b4, const float* __restrict__ bc2,
    float* __restrict__ out) {
    __shared__ __align__(16) u16 sH[128][HP];
    const int t = threadIdx.x;
    const int lane = t & 63;
    const int w = t >> 6;           // 8 waves
    const int lr = lane & 15, q = lane >> 4;
    const int wm = w & 1;           // batch-row half (64 rows each)
    const int wn = w >> 1;          // neuron-column quarter
    const long rb = (long)blockIdx.x * 128;

    const u16* WT1  = ws;
    const u16* WT2  = ws + 16384;
    const u16* WT3  = ws + 81920;
    const u16* WT4  = ws + 147456;
    const u16* WTc1 = ws + 151552;
    const u16* WTc2 = ws + 159744;

    // ---- positional encoding into sH[r][0..63] (col 63 = 1.0 for bias fold) ----
    {
        const int r = t & 127;
        const int g = t >> 7;       // 0..3
        const long row = rb + r;
        float xn[3];
#pragma unroll
        for (int c = 0; c < 3; ++c) xn[c] = pos[row * 3 + c] * (1.0f / 1.5f);
        if (g == 3) {
            sH[r][0] = f2b(xn[0]); sH[r][1] = f2b(xn[1]); sH[r][2] = f2b(xn[2]);
            sH[r][63] = 0x3F80;     // 1.0 — multiplies WT1[n][63] = b1[n]
#pragma unroll
            for (int c = 0; c < 3; ++c) {
                float tv = xn[c] * 512.f * INV2PI;  // degree 9
                sH[r][3 + 27 + c]  = f2b(sinrev(tv));
                sH[r][33 + 27 + c] = f2b(sinrev(tv + 0.25f));
            }
        } else {
#pragma unroll
            for (int dd = 0; dd < 3; ++dd) {
                const int d = g * 3 + dd;
                const float sc = (float)(1 << d);
#pragma unroll
                for (int c = 0; c < 3; ++c) {
                    float tv = xn[c] * sc * INV2PI;
                    sH[r][3 + d * 3 + c]  = f2b(sinrev(tv));
                    sH[r][33 + d * 3 + c] = f2b(sinrev(tv + 0.25f));
                }
            }
        }
    }
    __syncthreads();
    dense32<64, 2, true, false>(WT1, nullptr, sH, wm * 64, wn * 64, lane);
    __syncthreads();
    dense32<256, 2, true, true>(WT2, b2, sH, wm * 64, wn * 64, lane);
    __syncthreads();
    dense32<256, 2, true, true>(WT3, b3, sH, wm * 64, wn * 64, lane);
    __syncthreads();

    // ---- layer 4 (256 -> 16): all 8 waves, 16 rows each (16x16, n = lr) ----
    {
        f32x4 acc = {0.f, 0.f, 0.f, 0.f};
#pragma unroll
        for (int kt = 0; kt < 8; ++kt) {
            const short8 aF = *(const short8*)&sH[w * 16 + lr][kt * 32 + q * 8];
            const short8 bF = *(const short8*)(WT4 + lr * 256 + kt * 32 + q * 8);
            acc = __builtin_amdgcn_mfma_f32_16x16x32_bf16(aF, bF, acc, 0, 0, 0);
        }
        __syncthreads();
        {
            const float bi = b4[lr];
#pragma unroll
            for (int r = 0; r < 4; ++r) {
                const float v = acc[r] + bi;
                const int gm = w * 16 + q * 4 + r;
                if (lr == 0)
                    out[3 * (long)NPTS + rb + gm] = __expf(v - 1.f);
                else
                    sH[gm][lr - 1] = f2b(v);   // feat -> cols 0..14
            }
        }
        // ---- direction encoding -> sH[r][15..41], col42=1.0 (bias fold), 43..63 zero ----
        {
            const int r = t & 127;
            const int g = t >> 7;   // 0..3
            const long row = rb + r;
            const float dx = dir[row * 3 + 0];
            const float dy = dir[row * 3 + 1];
            const float dz = dir[row * 3 + 2];
            const float nrm = sqrtf(dx * dx + dy * dy + dz * dz);
            const float inv = 1.f / fmaxf(nrm, 1e-12f);
            const float dn[3] = {dx * inv, dy * inv, dz * inv};
            if (g == 0) {
                sH[r][15] = f2b(dn[0]); sH[r][16] = f2b(dn[1]); sH[r][17] = f2b(dn[2]);
                sH[r][42] = 0x3F80;  // 1.0 — multiplies WTc1[n][42] = bc1[n]
            }
            const float sc = (float)(1 << g);  // degree = g (0..3)
#pragma unroll
            for (int c = 0; c < 3; ++c) {
                float tv = dn[c] * sc * INV2PI;
                sH[r][18 + g * 3 + c] = f2b(sinrev(tv));
                sH[r][30 + g * 3 + c] = f2b(sinrev(tv + 0.25f));
            }
            for (int j = 43 + g; j < 64; j += 4) sH[r][j] = 0;
        }
    }
    __syncthreads();
    dense32<64, 1, true, false>(WTc1, nullptr, sH, wm * 64, wn * 32, lane);
    __syncthreads();

    // ---- color head (128 -> 3): all 8 waves, 16 rows each (16x16), sigmoid -> rgb ----
    {
        f32x4 acc = {0.f, 0.f, 0.f, 0.f};
#pragma unroll
        for (int kt = 0; kt < 4; ++kt) {
            const short8 aF = *(const short8*)&sH[w * 16 + lr][kt * 32 + q * 8];
            const short8 bF = *(const short8*)(WTc2 + lr * 128 + kt * 32 + q * 8);
            acc = __builtin_amdgcn_mfma_f32_16x16x32_bf16(aF, bF, acc, 0, 0, 0);
        }
        if (lr < 3) {
            const float bi = bc2[lr];
#pragma unroll
            for (int r = 0; r < 4; ++r) {
                const float v = acc[r] + bi;
                const float sg = 1.f / (1.f + __expf(-v));
                const int gm = w * 16 + q * 4 + r;
                out[(rb + gm) * 3 + lr] = sg;
            }
        }
    }
}

extern "C" void kernel_launch(void* const* d_in, const int* in_sizes, int n_in,
                              void* d_out, int out_size, void* d_ws, size_t ws_size,
                              hipStream_t stream) {
    const float* pos = (const float*)d_in[0];
    const float* dir = (const float*)d_in[1];
    const float* W1  = (const float*)d_in[2];
    const float* b1  = (const float*)d_in[3];
    const float* W2  = (const float*)d_in[4];
    const float* b2  = (const float*)d_in[5];
    const float* W3  = (const float*)d_in[6];
    const float* b3  = (const float*)d_in[7];
    const float* W4  = (const float*)d_in[8];
    const float* b4  = (const float*)d_in[9];
    const float* Wc1 = (const float*)d_in[10];
    const float* bc1 = (const float*)d_in[11];
    const float* Wc2 = (const float*)d_in[12];
    const float* bc2 = (const float*)d_in[13];
    u16* ws   = (u16*)d_ws;
    float* out = (float*)d_out;

    prep_weights<<<633, 256, 0, stream>>>(W1, b1, W2, W3, W4, Wc1, bc1, Wc2, ws);
    ngp_fused<<<NPTS / 128, 512, 0, stream>>>(pos, dir, ws, b2, b3, b4, bc2, out);
}